// Round 7
// baseline (36211.761 us; speedup 1.0000x reference)
//
#include <hip/hip_runtime.h>

// LSTM scan, persistent, TRUE-XCD-local groups + split-bf16 MFMA.
// T=512, B=64, D=256, H=512, K=768.
// Group = physical XCD (runtime-discovered via HW_REG_XCC_ID + atomic rank),
// 32 blocks/group, group owns 8 batches, block owns 16 units, wave = gate.
// h exchange: sc0 store (dirty local L2, ~200cy same-XCD visibility) PLUS
// sc0 sc1 write-through (LLC fallback + final memory). Consumers poll the h
// data itself (poison 0x7f7f7f7f) with sc0, escalating to sc1 after 256
// misses -> wrong theory degrades to LLC speed, never deadlock.
// Matmul: mfma_f32_16x16x32_bf16. x-part (K=256, h-independent) runs BEFORE
// the poll; h staged bf16-hi only (2 chains), x staged hi+lo (3 chains).

#define TSTEPS 512
#define BATCH 64
#define DIN 256
#define HID 512
#define KTOT 768
#define NB 8                 // batches per group
#define NU 16                // units per block
#define VROW 1064            // shorts/row: [h16 512 | xhi 256 | xlo 256 | pad 40]
                             // row stride = 532 dwords = 20 mod 32 (bank-uniform)
#define POISON 0x7f7f7f7fu   // 3.39e38f: h in (-1,1) can never be this

typedef __attribute__((ext_vector_type(8))) short bf16x8;
typedef __attribute__((ext_vector_type(4))) float f32x4;

__device__ __forceinline__ float4 l2_load4(const float* p) {   // bypass L1, read XCD L2
    float4 r; asm volatile("global_load_dwordx4 %0, %1, off sc0" : "=v"(r) : "v"(p)); return r;
}
__device__ __forceinline__ float4 llc_load4(const float* p) {  // bypass L1+L2, read LLC
    float4 r; asm volatile("global_load_dwordx4 %0, %1, off sc0 sc1" : "=v"(r) : "v"(p)); return r;
}
__device__ __forceinline__ void l2_store1(float* p, float v) {  // dirty local L2
    asm volatile("global_store_dword %0, %1, off sc0" :: "v"(p), "v"(v) : "memory");
}
__device__ __forceinline__ void llc_store1(float* p, float v) { // write-through to LLC
    asm volatile("global_store_dword %0, %1, off sc0 sc1" :: "v"(p), "v"(v) : "memory");
}
__device__ __forceinline__ unsigned short f2bf(float f) {       // RNE float->bf16
    unsigned u = __float_as_uint(f);
    return (unsigned short)((u + 0x7fffu + ((u >> 16) & 1u)) >> 16);
}

__global__ __launch_bounds__(256, 1)
void lstm_persistent(const float* __restrict__ seqs,
                     const float* __restrict__ h0,
                     const float* __restrict__ c0,
                     const float* __restrict__ Wi, const float* __restrict__ bi,
                     const float* __restrict__ Wf, const float* __restrict__ bff,
                     const float* __restrict__ Wg, const float* __restrict__ bg,
                     const float* __restrict__ Wo, const float* __restrict__ bo,
                     float* __restrict__ out,            // [T+1][B][H] then cT [B][H]
                     unsigned int* __restrict__ cnt)     // 8 per-XCD rank counters
{
    __shared__ __align__(16) short vv[NB * VROW];   // 17024 B
    __shared__ float red[4][16][12];                // 3072 B  [gate][unit][batch]
    __shared__ float c_s[128];                      // [bb*16+uu]
    __shared__ float bias_s[64];                    // [gate*16+uu]
    __shared__ int xcd_s, rblk_s;

    const int tid = threadIdx.x;

    // ---- runtime group discovery: group == physical XCD ----
    if (tid == 0) {
        unsigned xcc = 0;
        asm volatile("s_getreg_b32 %0, hwreg(HW_REG_XCC_ID)" : "=s"(xcc));
        xcc &= 7u;
        xcd_s = (int)xcc;
        rblk_s = (int)(atomicAdd(&cnt[xcc], 1u) & 31u);
    }
    __syncthreads();
    const int g = xcd_s;          // group: owns batches [8g, 8g+8)
    const int rblk = rblk_s;      // 0..31: owns units [16*rblk, 16*rblk+16)
    const int b0 = g * NB;
    const int u0 = rblk * NU;

    const int w   = tid >> 6;        // wave = gate
    const int l   = tid & 63;
    const int n16 = l & 15;          // MFMA m/n lane index (unit / batch col)
    const int khi = (l >> 4) & 3;    // MFMA k-group
    const int bbr = l & 7;           // B-frag batch row (lanes 8-15 duplicate)

    // ---- weights -> bf16 hi/lo fragments in registers (once) ----
    const float* Wsel = (w == 0) ? Wi : (w == 1) ? Wf : (w == 2) ? Wg : Wo;
    const float* wrow = Wsel + (size_t)(u0 + n16) * KTOT;
    bf16x8 whi[24], wlo[24];
#pragma unroll
    for (int kt = 0; kt < 24; ++kt) {
        const int k0 = kt * 32 + khi * 8;
        const float4 a = *reinterpret_cast<const float4*>(wrow + k0);
        const float4 b = *reinterpret_cast<const float4*>(wrow + k0 + 4);
        const float vals[8] = {a.x, a.y, a.z, a.w, b.x, b.y, b.z, b.w};
        bf16x8 h8, l8;
#pragma unroll
        for (int i = 0; i < 8; ++i) {
            const unsigned short hv = f2bf(vals[i]);
            h8[i] = (short)hv;
            l8[i] = (short)f2bf(vals[i] - __uint_as_float((unsigned)hv << 16));
        }
        whi[kt] = h8; wlo[kt] = l8;
    }

    if (tid < 64) {
        const int gg = tid >> 4, uu = tid & 15;
        const float* bsel = (gg == 0) ? bi : (gg == 1) ? bff : (gg == 2) ? bg : bo;
        bias_s[tid] = bsel[u0 + uu];
    }
    if (tid < 128) {   // c init + allhidden[0] = h0 slice (plain stores, never polled)
        const int uu = tid & 15, bb = tid >> 4;
        c_s[tid] = c0[(size_t)(b0 + bb) * HID + u0 + uu];
        out[(size_t)(b0 + bb) * HID + u0 + uu] = h0[(size_t)(b0 + bb) * HID + u0 + uu];
    }

    // ---- pre-loop staging: h0 (bf16-hi) and x0 (hi+lo) -> LDS ----
    {
        const int b = tid >> 5, k0 = (tid & 31) * 16;
        const float* hp = h0 + (size_t)(b0 + b) * HID + k0;
        float hv[16];
#pragma unroll
        for (int i = 0; i < 4; ++i) {
            const float4 t4 = reinterpret_cast<const float4*>(hp)[i];
            hv[4*i] = t4.x; hv[4*i+1] = t4.y; hv[4*i+2] = t4.z; hv[4*i+3] = t4.w;
        }
        bf16x8 h8a, h8b;
#pragma unroll
        for (int i = 0; i < 8; ++i) { h8a[i] = (short)f2bf(hv[i]); h8b[i] = (short)f2bf(hv[8+i]); }
        *reinterpret_cast<bf16x8*>(&vv[b * VROW + k0])     = h8a;
        *reinterpret_cast<bf16x8*>(&vv[b * VROW + k0 + 8]) = h8b;
    }
    if (tid < 128) {
        const int b = tid >> 4, kx = (tid & 15) * 16;
        const float* xp = seqs + (size_t)(b0 + b) * DIN + kx;
        float xv[16];
#pragma unroll
        for (int i = 0; i < 4; ++i) {
            const float4 t4 = reinterpret_cast<const float4*>(xp)[i];
            xv[4*i] = t4.x; xv[4*i+1] = t4.y; xv[4*i+2] = t4.z; xv[4*i+3] = t4.w;
        }
        bf16x8 h8a, h8b, l8a, l8b;
#pragma unroll
        for (int i = 0; i < 8; ++i) {
            const unsigned short h1 = f2bf(xv[i]);
            h8a[i] = (short)h1; l8a[i] = (short)f2bf(xv[i] - __uint_as_float((unsigned)h1 << 16));
            const unsigned short h2 = f2bf(xv[8+i]);
            h8b[i] = (short)h2; l8b[i] = (short)f2bf(xv[8+i] - __uint_as_float((unsigned)h2 << 16));
        }
        *reinterpret_cast<bf16x8*>(&vv[b * VROW + 512 + kx])     = h8a;
        *reinterpret_cast<bf16x8*>(&vv[b * VROW + 512 + kx + 8]) = h8b;
        *reinterpret_cast<bf16x8*>(&vv[b * VROW + 768 + kx])     = l8a;
        *reinterpret_cast<bf16x8*>(&vv[b * VROW + 768 + kx + 8]) = l8b;
    }
    __syncthreads();

    const short* vrow = &vv[bbr * VROW + khi * 8];

    for (int t = 0; t < TSTEPS; ++t) {
        // ---- A: x-part MFMA (h-independent; overlaps producers' tail) ----
        f32x4 aA = {0.f,0.f,0.f,0.f}, aB = {0.f,0.f,0.f,0.f}, aC = {0.f,0.f,0.f,0.f};
#pragma unroll
        for (int kt = 0; kt < 8; ++kt) {
            const bf16x8 bh = *reinterpret_cast<const bf16x8*>(vrow + 512 + kt * 32);
            const bf16x8 bl = *reinterpret_cast<const bf16x8*>(vrow + 768 + kt * 32);
            aA = __builtin_amdgcn_mfma_f32_16x16x32_bf16(whi[16 + kt], bh, aA, 0, 0, 0);
            aB = __builtin_amdgcn_mfma_f32_16x16x32_bf16(wlo[16 + kt], bh, aB, 0, 0, 0);
            aC = __builtin_amdgcn_mfma_f32_16x16x32_bf16(whi[16 + kt], bl, aC, 0, 0, 0);
        }

        // ---- C: poll h_t (t>=1): sc0 fast path, sc1 escalation ----
        const int pb = tid >> 5, pk = (tid & 31) * 16;
        if (t > 0) {
            const float* hp = out + (size_t)t * BATCH * HID + (size_t)(b0 + pb) * HID + pk;
            float4 hb[4];
            bool esc = false;
            unsigned miss = 0;
            for (;;) {
                if (!esc) {
#pragma unroll
                    for (int i = 0; i < 4; ++i) hb[i] = l2_load4(hp + 4 * i);
                } else {
#pragma unroll
                    for (int i = 0; i < 4; ++i) hb[i] = llc_load4(hp + 4 * i);
                }
                asm volatile("s_waitcnt vmcnt(0)" ::: "memory");
                __builtin_amdgcn_sched_barrier(0);
                bool ok = true;
#pragma unroll
                for (int i = 0; i < 4; ++i) {
                    ok &= (__float_as_uint(hb[i].x) != POISON);
                    ok &= (__float_as_uint(hb[i].y) != POISON);
                    ok &= (__float_as_uint(hb[i].z) != POISON);
                    ok &= (__float_as_uint(hb[i].w) != POISON);
                }
                if (ok) break;
                ++miss;
                if (miss == 256) esc = true;     // remote-XCD / LLC fallback
                if (miss > (1u << 20)) break;    // bounded: never hang
                __builtin_amdgcn_s_sleep(1);
            }
            // C2: cvt to bf16-hi, stage into LDS h region
            float hv[16];
#pragma unroll
            for (int i = 0; i < 4; ++i) {
                hv[4*i] = hb[i].x; hv[4*i+1] = hb[i].y; hv[4*i+2] = hb[i].z; hv[4*i+3] = hb[i].w;
            }
            bf16x8 h8a, h8b;
#pragma unroll
            for (int i = 0; i < 8; ++i) { h8a[i] = (short)f2bf(hv[i]); h8b[i] = (short)f2bf(hv[8+i]); }
            *reinterpret_cast<bf16x8*>(&vv[pb * VROW + pk])     = h8a;
            *reinterpret_cast<bf16x8*>(&vv[pb * VROW + pk + 8]) = h8b;
        }

        // ---- B: issue x_{t+1} loads (complete under D+E) ----
        float4 xr[4];
        const bool do_x = (t + 1 < TSTEPS) && (tid < 128);
        if (do_x) {
            const float* xp = seqs + (size_t)(t + 1) * BATCH * DIN
                            + (size_t)(b0 + (tid >> 4)) * DIN + (tid & 15) * 16;
#pragma unroll
            for (int i = 0; i < 4; ++i) xr[i] = reinterpret_cast<const float4*>(xp)[i];
        }
        __syncthreads();   // h_t fully staged

        // ---- D: h-part MFMA (2 chains, shared B-frag) ----
#pragma unroll
        for (int kt = 0; kt < 16; ++kt) {
            const bf16x8 bh = *reinterpret_cast<const bf16x8*>(vrow + kt * 32);
            aA = __builtin_amdgcn_mfma_f32_16x16x32_bf16(whi[kt], bh, aA, 0, 0, 0);
            aB = __builtin_amdgcn_mfma_f32_16x16x32_bf16(wlo[kt], bh, aB, 0, 0, 0);
        }
        const f32x4 gAcc = aA + aB + aC;
        if (n16 < 8) {
#pragma unroll
            for (int r = 0; r < 4; ++r)
                red[w][khi * 4 + r][n16] = gAcc[r];
        }
        __syncthreads();   // red ready

        // ---- E: elementwise + dual-visibility h store ----
        if (tid < 128) {
            const int uu = tid & 15, bb = tid >> 4;
            const float gi = red[0][uu][bb] + bias_s[uu];
            const float gf = red[1][uu][bb] + bias_s[16 + uu];
            const float gG = red[2][uu][bb] + bias_s[32 + uu];
            const float go = red[3][uu][bb] + bias_s[48 + uu];
            const float i_ = 1.f / (1.f + __expf(-gi));
            const float f_ = 1.f / (1.f + __expf(-gf));
            const float o_ = 1.f / (1.f + __expf(-go));
            float eg = __expf(-2.f * fabsf(gG));
            float tg = (1.f - eg) / (1.f + eg);
            tg = (gG < 0.f) ? -tg : tg;
            const float cn = f_ * c_s[tid] + i_ * tg;
            c_s[tid] = cn;
            float ec = __expf(-2.f * fabsf(cn));
            float tc = (1.f - ec) / (1.f + ec);
            tc = (cn < 0.f) ? -tc : tc;
            const float hn = o_ * tc;
            float* op = out + (size_t)(t + 1) * BATCH * HID + (size_t)(b0 + bb) * HID + u0 + uu;
            l2_store1(op, hn);    // fast same-XCD visibility (dirty L2)
            llc_store1(op, hn);   // LLC fallback + final memory (idempotent)
            if (t == TSTEPS - 1)
                out[(size_t)(TSTEPS + 1) * BATCH * HID + (size_t)(b0 + bb) * HID + u0 + uu] = cn;
        }

        // ---- F: x_{t+1} cvt -> LDS (x_t reads finished before barrier A') ----
        if (do_x) {
            const int b = tid >> 4, kx = (tid & 15) * 16;
            float xv[16];
#pragma unroll
            for (int i = 0; i < 4; ++i) {
                xv[4*i] = xr[i].x; xv[4*i+1] = xr[i].y; xv[4*i+2] = xr[i].z; xv[4*i+3] = xr[i].w;
            }
            bf16x8 h8a, h8b, l8a, l8b;
#pragma unroll
            for (int i = 0; i < 8; ++i) {
                const unsigned short h1 = f2bf(xv[i]);
                h8a[i] = (short)h1; l8a[i] = (short)f2bf(xv[i] - __uint_as_float((unsigned)h1 << 16));
                const unsigned short h2 = f2bf(xv[8+i]);
                h8b[i] = (short)h2; l8b[i] = (short)f2bf(xv[8+i] - __uint_as_float((unsigned)h2 << 16));
            }
            *reinterpret_cast<bf16x8*>(&vv[b * VROW + 512 + kx])     = h8a;
            *reinterpret_cast<bf16x8*>(&vv[b * VROW + 512 + kx + 8]) = h8b;
            *reinterpret_cast<bf16x8*>(&vv[b * VROW + 768 + kx])     = l8a;
            *reinterpret_cast<bf16x8*>(&vv[b * VROW + 768 + kx + 8]) = l8b;
        }
        __syncthreads();   // x_{t+1} staged; next iter's A may read
    }
}

extern "C" void kernel_launch(void* const* d_in, const int* in_sizes, int n_in,
                              void* d_out, int out_size, void* d_ws, size_t ws_size,
                              hipStream_t stream) {
    const float* seqs = (const float*)d_in[0];
    const float* h0   = (const float*)d_in[1];
    const float* c0   = (const float*)d_in[2];
    const float* Wi   = (const float*)d_in[3];
    const float* bi   = (const float*)d_in[4];
    const float* Wf   = (const float*)d_in[5];
    const float* bf   = (const float*)d_in[6];
    const float* Wg   = (const float*)d_in[7];
    const float* bg   = (const float*)d_in[8];
    const float* Wo   = (const float*)d_in[9];
    const float* bo   = (const float*)d_in[10];
    float* out = (float*)d_out;
    unsigned int* cnt = (unsigned int*)d_ws;

    // Zero the per-XCD rank counters and poison h[1..T] every launch.
    // Each h element is written exactly once per run -> data is the flag.
    hipMemsetAsync(cnt, 0, 8 * sizeof(unsigned int), stream);
    hipMemsetAsync((char*)out + (size_t)BATCH * HID * 4, 0x7f,
                   (size_t)TSTEPS * BATCH * HID * 4, stream);

    hipLaunchKernelGGL(lstm_persistent, dim3(256), dim3(256), 0, stream,
                       seqs, h0, c0, Wi, bi, Wf, bf, Wg, bg, Wo, bo, out, cnt);
}

// Round 9
// 1487.901 us; speedup vs baseline: 24.3375x; 24.3375x over previous
//
#include <hip/hip_runtime.h>

// LSTM scan, persistent, sentinel-poll sync + split-bf16 MFMA.
// T=512, B=64, D=256, H=512, K=768.
// 8 groups x 32 blocks (g = bid>>5). Group owns batches [8g,8g+8); block owns
// units [16r,16r+16); wave = gate. Weights register-resident (bf16 hi+lo).
// Sync lessons: cross-CU visibility ONLY at LLC (sc0 sc1) [R6/R7]; polling
// full slices congests the fabric [R5]; inline-asm loads MUST be followed by
// an explicit s_waitcnt vmcnt before use [R8 bug -> absmax 1.5].
// Producers store h (sc0 sc1) minus one sentinel, drain, then store the
// sentinel. Consumers poll 32 sentinel dwords (128 B, WITH waitcnt), then
// bulk-load the 16 KB slice once. Poison 0x7f7f7f7f = not-ready; h in (-1,1)
// never aliases it. out[1..T] re-poisoned every launch (replay-safe).
// Matmul: mfma_f32_16x16x32_bf16; x-part (K=256, 3 chains hi/lo) hoisted
// before the poll; h-part (K=512, 2 chains, h bf16-hi) after staging.

#define TSTEPS 512
#define BATCH 64
#define DIN 256
#define HID 512
#define KTOT 768
#define BHID (BATCH * HID)   // 32768
#define NB 8                 // batches per group
#define NU 16                // units per block
#define VROW 1064            // shorts/row: [h 512 | xhi 256 | xlo 256 | pad 40]
#define POISON 0x7f7f7f7fu

typedef __attribute__((ext_vector_type(8))) short bf16x8;
typedef __attribute__((ext_vector_type(4))) float f32x4;

__device__ __forceinline__ float4 llc_load4(const float* p) {
    float4 r; asm volatile("global_load_dwordx4 %0, %1, off sc0 sc1" : "=v"(r) : "v"(p)); return r;
}
__device__ __forceinline__ float llc_load1(const float* p) {
    float r; asm volatile("global_load_dword %0, %1, off sc0 sc1" : "=v"(r) : "v"(p)); return r;
}
__device__ __forceinline__ void llc_store1(float* p, float v) {
    asm volatile("global_store_dword %0, %1, off sc0 sc1" :: "v"(p), "v"(v) : "memory");
}
__device__ __forceinline__ unsigned short f2bf(float f) {   // RNE float->bf16
    unsigned u = __float_as_uint(f);
    return (unsigned short)((u + 0x7fffu + ((u >> 16) & 1u)) >> 16);
}

__global__ __launch_bounds__(256, 1)
void lstm_persistent(const float* __restrict__ seqs,
                     const float* __restrict__ h0,
                     const float* __restrict__ c0,
                     const float* __restrict__ Wi, const float* __restrict__ bi,
                     const float* __restrict__ Wf, const float* __restrict__ bff,
                     const float* __restrict__ Wg, const float* __restrict__ bg,
                     const float* __restrict__ Wo, const float* __restrict__ bo,
                     float* __restrict__ out)   // [T+2][B][H]: h0, h1..hT, cT
{
    __shared__ __align__(16) short vv[NB * VROW];   // 17024 B
    __shared__ float red[4][16][12];                // [gate][unit][batch]
    __shared__ float c_s[128];                      // [bb*16+uu]
    __shared__ float bias_s[64];                    // [gate*16+uu]

    const int tid  = threadIdx.x;
    const int bid  = blockIdx.x;
    const int g    = bid >> 5;         // group 0..7: batches [8g, 8g+8)
    const int rblk = bid & 31;         // 0..31: units [16r, 16r+16)
    const int b0 = g * NB;
    const int u0 = rblk * NU;

    const int w   = tid >> 6;          // wave = gate
    const int l   = tid & 63;
    const int n16 = l & 15;            // A-frag row (unit) / D col
    const int khi = (l >> 4) & 3;      // k-subgroup
    const int bbr = l & 7;             // B-frag batch row (8-15 broadcast-dup)

    // ---- weights -> bf16 hi/lo fragments (once) ----
    const float* Wsel = (w == 0) ? Wi : (w == 1) ? Wf : (w == 2) ? Wg : Wo;
    const float* wrow = Wsel + (size_t)(u0 + n16) * KTOT;
    bf16x8 whi[24], wlo[24];
#pragma unroll
    for (int kt = 0; kt < 24; ++kt) {
        const int k0 = kt * 32 + khi * 8;
        const float4 a = *reinterpret_cast<const float4*>(wrow + k0);
        const float4 b = *reinterpret_cast<const float4*>(wrow + k0 + 4);
        const float vals[8] = {a.x, a.y, a.z, a.w, b.x, b.y, b.z, b.w};
        bf16x8 h8, l8;
#pragma unroll
        for (int i = 0; i < 8; ++i) {
            const unsigned short hv = f2bf(vals[i]);
            h8[i] = (short)hv;
            l8[i] = (short)f2bf(vals[i] - __uint_as_float((unsigned)hv << 16));
        }
        whi[kt] = h8; wlo[kt] = l8;
    }

    if (tid < 64) {
        const int gg = tid >> 4, uu = tid & 15;
        const float* bsel = (gg == 0) ? bi : (gg == 1) ? bff : (gg == 2) ? bg : bo;
        bias_s[tid] = bsel[u0 + uu];
    }
    if (tid < 128) {   // c init + allhidden[0] = h0 slice (plain; never polled)
        const int uu = tid & 15, bb = tid >> 4;
        c_s[tid] = c0[(size_t)(b0 + bb) * HID + u0 + uu];
        out[(size_t)(b0 + bb) * HID + u0 + uu] = h0[(size_t)(b0 + bb) * HID + u0 + uu];
    }

    // ---- pre-loop staging: h0 (bf16-hi) and x0 (hi+lo) -> LDS ----
    {
        const int b = tid >> 5, k0 = (tid & 31) * 16;
        const float* hp = h0 + (size_t)(b0 + b) * HID + k0;
        float hv[16];
#pragma unroll
        for (int i = 0; i < 4; ++i) {
            const float4 t4 = reinterpret_cast<const float4*>(hp)[i];
            hv[4*i] = t4.x; hv[4*i+1] = t4.y; hv[4*i+2] = t4.z; hv[4*i+3] = t4.w;
        }
        bf16x8 a8, b8;
#pragma unroll
        for (int i = 0; i < 8; ++i) { a8[i] = (short)f2bf(hv[i]); b8[i] = (short)f2bf(hv[8+i]); }
        *reinterpret_cast<bf16x8*>(&vv[b * VROW + k0])     = a8;
        *reinterpret_cast<bf16x8*>(&vv[b * VROW + k0 + 8]) = b8;
    }
    if (tid < 128) {
        const int b = tid >> 4, kx = (tid & 15) * 16;
        const float* xp = seqs + (size_t)(b0 + b) * DIN + kx;
        float xv[16];
#pragma unroll
        for (int i = 0; i < 4; ++i) {
            const float4 t4 = reinterpret_cast<const float4*>(xp)[i];
            xv[4*i] = t4.x; xv[4*i+1] = t4.y; xv[4*i+2] = t4.z; xv[4*i+3] = t4.w;
        }
        bf16x8 a8, b8, la8, lb8;
#pragma unroll
        for (int i = 0; i < 8; ++i) {
            const unsigned short h1 = f2bf(xv[i]);
            a8[i] = (short)h1; la8[i] = (short)f2bf(xv[i] - __uint_as_float((unsigned)h1 << 16));
            const unsigned short h2 = f2bf(xv[8+i]);
            b8[i] = (short)h2; lb8[i] = (short)f2bf(xv[8+i] - __uint_as_float((unsigned)h2 << 16));
        }
        *reinterpret_cast<bf16x8*>(&vv[b * VROW + 512 + kx])     = a8;
        *reinterpret_cast<bf16x8*>(&vv[b * VROW + 512 + kx + 8]) = b8;
        *reinterpret_cast<bf16x8*>(&vv[b * VROW + 768 + kx])     = la8;
        *reinterpret_cast<bf16x8*>(&vv[b * VROW + 768 + kx + 8]) = lb8;
    }
    __syncthreads();

    const short* vrow = &vv[bbr * VROW + khi * 8];

    for (int t = 0; t < TSTEPS; ++t) {
        // ---- A: x-part MFMA (uses x_t; overlaps other blocks' h_t tails) ----
        f32x4 aA = {0.f,0.f,0.f,0.f}, aB = {0.f,0.f,0.f,0.f}, aC = {0.f,0.f,0.f,0.f};
#pragma unroll
        for (int kt = 0; kt < 8; ++kt) {
            const bf16x8 bh = *reinterpret_cast<const bf16x8*>(vrow + 512 + kt * 32);
            const bf16x8 bl = *reinterpret_cast<const bf16x8*>(vrow + 768 + kt * 32);
            aA = __builtin_amdgcn_mfma_f32_16x16x32_bf16(whi[16 + kt], bh, aA, 0, 0, 0);
            aB = __builtin_amdgcn_mfma_f32_16x16x32_bf16(wlo[16 + kt], bh, aB, 0, 0, 0);
            aC = __builtin_amdgcn_mfma_f32_16x16x32_bf16(whi[16 + kt], bl, aC, 0, 0, 0);
        }

        // ---- B: issue x_{t+1} loads (complete under C/D) ----
        float4 xr[4];
        const bool do_x = (t + 1 < TSTEPS) && (tid < 128);
        if (do_x) {
            const float* xp = seqs + (size_t)(t + 1) * BATCH * DIN
                            + (size_t)(b0 + (tid >> 4)) * DIN + (tid & 15) * 16;
#pragma unroll
            for (int i = 0; i < 4; ++i) xr[i] = reinterpret_cast<const float4*>(xp)[i];
        }

        // ---- C (t>0): sentinel poll (WITH waitcnt!), then one bulk fetch ----
        if (t > 0) {
            const float* srow = out + (size_t)t * BHID + (size_t)(b0 + 7) * HID;
            unsigned miss = 0;
            for (;;) {                       // each wave polls independently
                bool ok = true;
                if (l < 32) {
                    const float s = llc_load1(srow + l * 16 + 15);
                    // R8 bug fix: the asm load's dest reg is NOT auto-waited;
                    // without this the comparison reads garbage.
                    asm volatile("s_waitcnt vmcnt(0)" ::: "memory");
                    __builtin_amdgcn_sched_barrier(0);
                    ok = (__float_as_uint(s) != POISON);
                }
                if (__all(ok)) break;
                if (++miss > (1u << 20)) break;   // bounded: never hang
                __builtin_amdgcn_s_sleep(1);
            }
            // bulk fetch this block's 16 KB h slice (sentinels included, set)
            const int b = tid >> 5, k0 = (tid & 31) * 16;
            const float* hp = out + (size_t)t * BHID + (size_t)(b0 + b) * HID + k0;
            float4 hb[4];
#pragma unroll
            for (int i = 0; i < 4; ++i) hb[i] = llc_load4(hp + 4 * i);
            asm volatile("s_waitcnt vmcnt(0)" ::: "memory");
            __builtin_amdgcn_sched_barrier(0);
            float hv[16];
#pragma unroll
            for (int i = 0; i < 4; ++i) {
                hv[4*i] = hb[i].x; hv[4*i+1] = hb[i].y; hv[4*i+2] = hb[i].z; hv[4*i+3] = hb[i].w;
            }
            bf16x8 a8, b8;
#pragma unroll
            for (int i = 0; i < 8; ++i) { a8[i] = (short)f2bf(hv[i]); b8[i] = (short)f2bf(hv[8+i]); }
            *reinterpret_cast<bf16x8*>(&vv[b * VROW + k0])     = a8;
            *reinterpret_cast<bf16x8*>(&vv[b * VROW + k0 + 8]) = b8;
        }
        __syncthreads();   // h_t staged for all waves

        // ---- D: h-part MFMA (2 chains, h bf16-hi) ----
#pragma unroll
        for (int kt = 0; kt < 16; ++kt) {
            const bf16x8 bh = *reinterpret_cast<const bf16x8*>(vrow + kt * 32);
            aA = __builtin_amdgcn_mfma_f32_16x16x32_bf16(whi[kt], bh, aA, 0, 0, 0);
            aB = __builtin_amdgcn_mfma_f32_16x16x32_bf16(wlo[kt], bh, aB, 0, 0, 0);
        }
        const f32x4 gAcc = aA + aB + aC;
        if (n16 < 8) {
#pragma unroll
            for (int r = 0; r < 4; ++r)
                red[w][khi * 4 + r][n16] = gAcc[r];
        }
        __syncthreads();   // red ready

        // ---- E: elementwise + h store (sentinel element deferred) ----
        float hn127 = 0.f;
        float* op127 = nullptr;
        if (tid < 128) {
            const int uu = tid & 15, bb = tid >> 4;
            const float gi = red[0][uu][bb] + bias_s[uu];
            const float gf = red[1][uu][bb] + bias_s[16 + uu];
            const float gG = red[2][uu][bb] + bias_s[32 + uu];
            const float go = red[3][uu][bb] + bias_s[48 + uu];
            const float i_ = 1.f / (1.f + __expf(-gi));
            const float f_ = 1.f / (1.f + __expf(-gf));
            const float o_ = 1.f / (1.f + __expf(-go));
            float eg = __expf(-2.f * fabsf(gG));
            float tg = (1.f - eg) / (1.f + eg);
            tg = (gG < 0.f) ? -tg : tg;
            const float cn = f_ * c_s[tid] + i_ * tg;
            c_s[tid] = cn;
            float ec = __expf(-2.f * fabsf(cn));
            float tc = (1.f - ec) / (1.f + ec);
            tc = (cn < 0.f) ? -tc : tc;
            const float hn = o_ * tc;
            float* op = out + (size_t)(t + 1) * BHID + (size_t)(b0 + bb) * HID + u0 + uu;
            if (tid != 127) llc_store1(op, hn);
            else { hn127 = hn; op127 = op; }    // sentinel: store after drain
            if (t == TSTEPS - 1)
                out[(size_t)(TSTEPS + 1) * BHID + (size_t)(b0 + bb) * HID + u0 + uu] = cn;
        }

        // ---- F: x_{t+1} cvt -> LDS ----
        if (do_x) {
            const int b = tid >> 4, kx = (tid & 15) * 16;
            float xv[16];
#pragma unroll
            for (int i = 0; i < 4; ++i) {
                xv[4*i] = xr[i].x; xv[4*i+1] = xr[i].y; xv[4*i+2] = xr[i].z; xv[4*i+3] = xr[i].w;
            }
            bf16x8 a8, b8, la8, lb8;
#pragma unroll
            for (int i = 0; i < 8; ++i) {
                const unsigned short h1 = f2bf(xv[i]);
                a8[i] = (short)h1; la8[i] = (short)f2bf(xv[i] - __uint_as_float((unsigned)h1 << 16));
                const unsigned short h2 = f2bf(xv[8+i]);
                b8[i] = (short)h2; lb8[i] = (short)f2bf(xv[8+i] - __uint_as_float((unsigned)h2 << 16));
            }
            *reinterpret_cast<bf16x8*>(&vv[b * VROW + 512 + kx])     = a8;
            *reinterpret_cast<bf16x8*>(&vv[b * VROW + 512 + kx + 8]) = b8;
            *reinterpret_cast<bf16x8*>(&vv[b * VROW + 768 + kx])     = la8;
            *reinterpret_cast<bf16x8*>(&vv[b * VROW + 768 + kx + 8]) = lb8;
        }

        // ---- G: drain h stores block-wide, then release the sentinel ----
        asm volatile("s_waitcnt vmcnt(0)" ::: "memory");
        __syncthreads();
        if (tid == 127) llc_store1(op127, hn127);
    }
}

extern "C" void kernel_launch(void* const* d_in, const int* in_sizes, int n_in,
                              void* d_out, int out_size, void* d_ws, size_t ws_size,
                              hipStream_t stream) {
    const float* seqs = (const float*)d_in[0];
    const float* h0   = (const float*)d_in[1];
    const float* c0   = (const float*)d_in[2];
    const float* Wi   = (const float*)d_in[3];
    const float* bi   = (const float*)d_in[4];
    const float* Wf   = (const float*)d_in[5];
    const float* bf   = (const float*)d_in[6];
    const float* Wg   = (const float*)d_in[7];
    const float* bg   = (const float*)d_in[8];
    const float* Wo   = (const float*)d_in[9];
    const float* bo   = (const float*)d_in[10];
    float* out = (float*)d_out;

    // Poison h[1..T] every launch: each element is written exactly once per
    // run, so the data itself is the readiness flag (graph-replay safe).
    hipMemsetAsync((char*)out + (size_t)BHID * 4, 0x7f,
                   (size_t)TSTEPS * BHID * 4, stream);

    hipLaunchKernelGGL(lstm_persistent, dim3(256), dim3(256), 0, stream,
                       seqs, h0, c0, Wi, bi, Wf, bf, Wg, bg, Wo, bo, out);
}

// Round 10
// 1363.722 us; speedup vs baseline: 26.5536x; 1.0911x over previous
//
#include <hip/hip_runtime.h>

// LSTM scan, persistent, per-element-poison sync + split-bf16 MFMA,
// all-gates-in-lane epilogue. T=512, B=64, D=256, H=512, K=768.
// 8 groups x 32 blocks (g=bid>>5). Group owns batches [8g,8g+8); block owns
// units [16r,16r+16); wave wv owns units u0+4wv..u0+4wv+3 (NOT gates).
// A-row encoding row = u_local*4 + gate  =>  D fragment row khi*4+r gives
// lane ALL FOUR gates of (unit=u0+4wv+khi, batch=n16): elementwise is fully
// lane-local (no red LDS, no c_s, no bias LDS, one less barrier).
// Sync: h elements are self-flagging (poison 0x7f7f7f7f, each written once
// per run). Producers fire-and-forget sc0 sc1 stores (no drain, no sentinel);
// consumers speculatively bulk-load their slice and retry per-thread until
// their own 16 values are non-poison. ~1.5 LLC RTT handoff.
// Lessons kept: LLC-only visibility (R6/R7); asm loads need explicit vmcnt
// before use (R8); out[1..T] re-poisoned every launch (replay-safe).

#define TSTEPS 512
#define BATCH 64
#define DIN 256
#define HID 512
#define KTOT 768
#define BHID (BATCH * HID)   // 32768
#define NB 8                 // batches per group
#define NU 16                // units per block
#define VROW 1064            // shorts/row: [h 512 | xhi 256 | xlo 256 | pad 40]
#define POISON 0x7f7f7f7fu

typedef __attribute__((ext_vector_type(8))) short bf16x8;
typedef __attribute__((ext_vector_type(4))) float f32x4;

__device__ __forceinline__ float4 llc_load4(const float* p) {
    float4 r; asm volatile("global_load_dwordx4 %0, %1, off sc0 sc1" : "=v"(r) : "v"(p)); return r;
}
__device__ __forceinline__ void llc_store1(float* p, float v) {
    asm volatile("global_store_dword %0, %1, off sc0 sc1" :: "v"(p), "v"(v) : "memory");
}
__device__ __forceinline__ unsigned short f2bf(float f) {   // RNE float->bf16
    unsigned u = __float_as_uint(f);
    return (unsigned short)((u + 0x7fffu + ((u >> 16) & 1u)) >> 16);
}

__global__ __launch_bounds__(256, 1)
void lstm_persistent(const float* __restrict__ seqs,
                     const float* __restrict__ h0,
                     const float* __restrict__ c0,
                     const float* __restrict__ Wi, const float* __restrict__ bi,
                     const float* __restrict__ Wf, const float* __restrict__ bff,
                     const float* __restrict__ Wg, const float* __restrict__ bg,
                     const float* __restrict__ Wo, const float* __restrict__ bo,
                     float* __restrict__ out)   // [T+2][B][H]: h0, h1..hT, cT
{
    __shared__ __align__(16) short vv[NB * VROW];   // 17024 B — only LDS left

    const int tid  = threadIdx.x;
    const int bid  = blockIdx.x;
    const int g    = bid >> 5;         // group 0..7: batches [8g, 8g+8)
    const int rblk = bid & 31;         // 0..31: units [16r, 16r+16)
    const int b0 = g * NB;
    const int u0 = rblk * NU;

    const int wv  = tid >> 6;          // wave: owns units u0+4wv .. +3
    const int l   = tid & 63;
    const int n16 = l & 15;            // A row idx / D col (batch)
    const int khi = (l >> 4) & 3;      // k-subgroup / D row group (unit)
    const int bbr = l & 7;             // B-frag batch row (8-15 broadcast-dup)

    // ---- weights: lane n16 loads row (gate = n16&3, u_local = n16>>2) ----
    const int gsel = n16 & 3;
    const float* Wsel = (gsel == 0) ? Wi : (gsel == 1) ? Wf : (gsel == 2) ? Wg : Wo;
    const float* wrow = Wsel + (size_t)(u0 + 4 * wv + (n16 >> 2)) * KTOT;
    bf16x8 whi[24], wlo[24];
#pragma unroll
    for (int kt = 0; kt < 24; ++kt) {
        const int k0 = kt * 32 + khi * 8;
        const float4 a = *reinterpret_cast<const float4*>(wrow + k0);
        const float4 b = *reinterpret_cast<const float4*>(wrow + k0 + 4);
        const float vals[8] = {a.x, a.y, a.z, a.w, b.x, b.y, b.z, b.w};
        bf16x8 h8, l8;
#pragma unroll
        for (int i = 0; i < 8; ++i) {
            const unsigned short hv = f2bf(vals[i]);
            h8[i] = (short)hv;
            l8[i] = (short)f2bf(vals[i] - __uint_as_float((unsigned)hv << 16));
        }
        whi[kt] = h8; wlo[kt] = l8;
    }

    // ---- per-lane epilogue state: biases + c (unit_d, batch_d) ----
    const int unit_d  = u0 + 4 * wv + khi;
    const int batch_d = b0 + (n16 & 7);          // clamped for lanes 8-15 (unused)
    const float bI = bi[unit_d],  bF = bff[unit_d];
    const float bG = bg[unit_d],  bO = bo[unit_d];
    float creg = c0[(size_t)batch_d * HID + unit_d];

    if (tid < 128) {   // allhidden[0] = h0 slice (plain; never polled)
        const int uu = tid & 15, bb = tid >> 4;
        out[(size_t)(b0 + bb) * HID + u0 + uu] = h0[(size_t)(b0 + bb) * HID + u0 + uu];
    }

    // ---- pre-loop staging: h0 (bf16-hi) and x0 (hi+lo) -> LDS ----
    {
        const int b = tid >> 5, k0 = (tid & 31) * 16;
        const float* hp = h0 + (size_t)(b0 + b) * HID + k0;
        float hv[16];
#pragma unroll
        for (int i = 0; i < 4; ++i) {
            const float4 t4 = reinterpret_cast<const float4*>(hp)[i];
            hv[4*i] = t4.x; hv[4*i+1] = t4.y; hv[4*i+2] = t4.z; hv[4*i+3] = t4.w;
        }
        bf16x8 a8, b8;
#pragma unroll
        for (int i = 0; i < 8; ++i) { a8[i] = (short)f2bf(hv[i]); b8[i] = (short)f2bf(hv[8+i]); }
        *reinterpret_cast<bf16x8*>(&vv[b * VROW + k0])     = a8;
        *reinterpret_cast<bf16x8*>(&vv[b * VROW + k0 + 8]) = b8;
    }
    if (tid < 128) {
        const int b = tid >> 4, kx = (tid & 15) * 16;
        const float* xp = seqs + (size_t)(b0 + b) * DIN + kx;
        float xv[16];
#pragma unroll
        for (int i = 0; i < 4; ++i) {
            const float4 t4 = reinterpret_cast<const float4*>(xp)[i];
            xv[4*i] = t4.x; xv[4*i+1] = t4.y; xv[4*i+2] = t4.z; xv[4*i+3] = t4.w;
        }
        bf16x8 a8, b8, la8, lb8;
#pragma unroll
        for (int i = 0; i < 8; ++i) {
            const unsigned short h1 = f2bf(xv[i]);
            a8[i] = (short)h1; la8[i] = (short)f2bf(xv[i] - __uint_as_float((unsigned)h1 << 16));
            const unsigned short h2 = f2bf(xv[8+i]);
            b8[i] = (short)h2; lb8[i] = (short)f2bf(xv[8+i] - __uint_as_float((unsigned)h2 << 16));
        }
        *reinterpret_cast<bf16x8*>(&vv[b * VROW + 512 + kx])     = a8;
        *reinterpret_cast<bf16x8*>(&vv[b * VROW + 512 + kx + 8]) = b8;
        *reinterpret_cast<bf16x8*>(&vv[b * VROW + 768 + kx])     = la8;
        *reinterpret_cast<bf16x8*>(&vv[b * VROW + 768 + kx + 8]) = lb8;
    }
    __syncthreads();

    const short* vrow = &vv[bbr * VROW + khi * 8];

    for (int t = 0; t < TSTEPS; ++t) {
        // ---- A: x-part MFMA (uses x_t; overlaps other blocks' h_t tails) ----
        f32x4 aA = {0.f,0.f,0.f,0.f}, aB = {0.f,0.f,0.f,0.f}, aC = {0.f,0.f,0.f,0.f};
#pragma unroll
        for (int kt = 0; kt < 8; ++kt) {
            const bf16x8 bh = *reinterpret_cast<const bf16x8*>(vrow + 512 + kt * 32);
            const bf16x8 bl = *reinterpret_cast<const bf16x8*>(vrow + 768 + kt * 32);
            aA = __builtin_amdgcn_mfma_f32_16x16x32_bf16(whi[16 + kt], bh, aA, 0, 0, 0);
            aB = __builtin_amdgcn_mfma_f32_16x16x32_bf16(wlo[16 + kt], bh, aB, 0, 0, 0);
            aC = __builtin_amdgcn_mfma_f32_16x16x32_bf16(whi[16 + kt], bl, aC, 0, 0, 0);
        }

        // ---- B: issue x_{t+1} loads (complete under C/D) ----
        float4 xr[4];
        const bool do_x = (t + 1 < TSTEPS) && (tid < 128);
        if (do_x) {
            const float* xp = seqs + (size_t)(t + 1) * BATCH * DIN
                            + (size_t)(b0 + (tid >> 4)) * DIN + (tid & 15) * 16;
#pragma unroll
            for (int i = 0; i < 4; ++i) xr[i] = reinterpret_cast<const float4*>(xp)[i];
        }

        // ---- C (t>0): speculative bulk poll — data is its own flag ----
        if (t > 0) {
            const int b = tid >> 5, k0 = (tid & 31) * 16;
            const float* hp = out + (size_t)t * BHID + (size_t)(b0 + b) * HID + k0;
            float4 hb[4];
            unsigned miss = 0;
            for (;;) {
#pragma unroll
                for (int i = 0; i < 4; ++i) hb[i] = llc_load4(hp + 4 * i);
                asm volatile("s_waitcnt vmcnt(0)" ::: "memory");
                __builtin_amdgcn_sched_barrier(0);
                bool ok = true;
#pragma unroll
                for (int i = 0; i < 4; ++i) {
                    ok &= (__float_as_uint(hb[i].x) != POISON);
                    ok &= (__float_as_uint(hb[i].y) != POISON);
                    ok &= (__float_as_uint(hb[i].z) != POISON);
                    ok &= (__float_as_uint(hb[i].w) != POISON);
                }
                if (ok) break;                    // per-thread readiness only
                if (++miss > (1u << 20)) break;   // bounded: never hang
            }
            float hv[16];
#pragma unroll
            for (int i = 0; i < 4; ++i) {
                hv[4*i] = hb[i].x; hv[4*i+1] = hb[i].y; hv[4*i+2] = hb[i].z; hv[4*i+3] = hb[i].w;
            }
            bf16x8 a8, b8;
#pragma unroll
            for (int i = 0; i < 8; ++i) { a8[i] = (short)f2bf(hv[i]); b8[i] = (short)f2bf(hv[8+i]); }
            *reinterpret_cast<bf16x8*>(&vv[b * VROW + k0])     = a8;
            *reinterpret_cast<bf16x8*>(&vv[b * VROW + k0 + 8]) = b8;
        }
        __syncthreads();   // h_t staged block-wide

        // ---- D: h-part MFMA (2 chains, h bf16-hi) ----
#pragma unroll
        for (int kt = 0; kt < 16; ++kt) {
            const bf16x8 bh = *reinterpret_cast<const bf16x8*>(vrow + kt * 32);
            aA = __builtin_amdgcn_mfma_f32_16x16x32_bf16(whi[kt], bh, aA, 0, 0, 0);
            aB = __builtin_amdgcn_mfma_f32_16x16x32_bf16(wlo[kt], bh, aB, 0, 0, 0);
        }
        const f32x4 gA = aA + aB + aC;   // gA[r] = gate r of (unit_d, batch n16)

        // ---- E: lane-local elementwise + fire-and-forget h store ----
        if (n16 < 8) {
            const float gi = gA[0] + bI;
            const float gf = gA[1] + bF;
            const float gG = gA[2] + bG;
            const float go = gA[3] + bO;
            const float i_ = 1.f / (1.f + __expf(-gi));
            const float f_ = 1.f / (1.f + __expf(-gf));
            const float o_ = 1.f / (1.f + __expf(-go));
            float eg = __expf(-2.f * fabsf(gG));
            float tg = (1.f - eg) / (1.f + eg);
            tg = (gG < 0.f) ? -tg : tg;
            creg = f_ * creg + i_ * tg;
            float ec = __expf(-2.f * fabsf(creg));
            float tc = (1.f - ec) / (1.f + ec);
            tc = (creg < 0.f) ? -tc : tc;
            const float hn = o_ * tc;
            llc_store1(out + (size_t)(t + 1) * BHID + (size_t)batch_d * HID + unit_d, hn);
            if (t == TSTEPS - 1)
                out[(size_t)(TSTEPS + 1) * BHID + (size_t)batch_d * HID + unit_d] = creg;
        }

        // ---- F: x_{t+1} cvt -> LDS ----
        if (do_x) {
            const int b = tid >> 4, kx = (tid & 15) * 16;
            float xv[16];
#pragma unroll
            for (int i = 0; i < 4; ++i) {
                xv[4*i] = xr[i].x; xv[4*i+1] = xr[i].y; xv[4*i+2] = xr[i].z; xv[4*i+3] = xr[i].w;
            }
            bf16x8 a8, b8, la8, lb8;
#pragma unroll
            for (int i = 0; i < 8; ++i) {
                const unsigned short h1 = f2bf(xv[i]);
                a8[i] = (short)h1; la8[i] = (short)f2bf(xv[i] - __uint_as_float((unsigned)h1 << 16));
                const unsigned short h2 = f2bf(xv[8+i]);
                b8[i] = (short)h2; lb8[i] = (short)f2bf(xv[8+i] - __uint_as_float((unsigned)h2 << 16));
            }
            *reinterpret_cast<bf16x8*>(&vv[b * VROW + 512 + kx])     = a8;
            *reinterpret_cast<bf16x8*>(&vv[b * VROW + 512 + kx + 8]) = b8;
            *reinterpret_cast<bf16x8*>(&vv[b * VROW + 768 + kx])     = la8;
            *reinterpret_cast<bf16x8*>(&vv[b * VROW + 768 + kx + 8]) = lb8;
        }
        __syncthreads();   // x_{t+1} staged; h region free for next C
    }
}

extern "C" void kernel_launch(void* const* d_in, const int* in_sizes, int n_in,
                              void* d_out, int out_size, void* d_ws, size_t ws_size,
                              hipStream_t stream) {
    const float* seqs = (const float*)d_in[0];
    const float* h0   = (const float*)d_in[1];
    const float* c0   = (const float*)d_in[2];
    const float* Wi   = (const float*)d_in[3];
    const float* bi   = (const float*)d_in[4];
    const float* Wf   = (const float*)d_in[5];
    const float* bf   = (const float*)d_in[6];
    const float* Wg   = (const float*)d_in[7];
    const float* bg   = (const float*)d_in[8];
    const float* Wo   = (const float*)d_in[9];
    const float* bo   = (const float*)d_in[10];
    float* out = (float*)d_out;

    // Poison h[1..T] every launch: each element is written exactly once per
    // run, so the data itself is the readiness flag (graph-replay safe).
    hipMemsetAsync((char*)out + (size_t)BHID * 4, 0x7f,
                   (size_t)TSTEPS * BHID * 4, stream);

    hipLaunchKernelGGL(lstm_persistent, dim3(256), dim3(256), 0, stream,
                       seqs, h0, c0, Wi, bi, Wf, bf, Wg, bg, Wo, bo, out);
}

// Round 14
// 1355.204 us; speedup vs baseline: 26.7205x; 1.0063x over previous
//
#include <hip/hip_runtime.h>

// LSTM scan, persistent, per-element-poison sync + split-bf16 MFMA,
// all-gates-in-lane epilogue. T=512, B=64, D=256, H=512, K=768.
// == R10 architecture (proven: passed, 1364us) + "=&v" early-clobber + poll
// sleep. R11-R13 post-mortem: bf16 exchange via d_ws NaN'd 3 rounds; consumers
// stage the registers they check, so poison can only enter via POLL TIMEOUT
// -> the sub-dword / packed write-through stores never became visible to
// sc0 sc1 loads. Lesson: only plain DWORD sc0 sc1 stores are proven visible
// cross-XCD at the LLC on this part. Exchange stays f32-dword via out.
// 8 groups x 32 blocks (g=bid>>5). Group owns batches [8g,8g+8); block owns
// units [16r,16r+16); wave wv owns units u0+4wv..+3 (NOT gates).
// A-row encoding row = u_local*4 + gate  =>  D fragment row khi*4+r gives
// lane ALL FOUR gates of (unit=u0+4wv+khi, batch=n16): elementwise is fully
// lane-local (no red LDS, no c_s, no bias LDS, one less barrier).
// Sync: h elements are self-flagging (poison 0x7f7f7f7f, each written once
// per run). Producers fire-and-forget sc0 sc1 dword stores; consumers
// speculatively bulk-load their slice and retry per-thread until their own
// 16 values are non-poison. ~1.5 LLC RTT handoff.
// Lessons kept: LLC-only cross-CU visibility (R6/R7); explicit vmcnt after
// asm loads (R8); bounded polls; no drains/sentinels (R10).

#define TSTEPS 512
#define BATCH 64
#define DIN 256
#define HID 512
#define KTOT 768
#define BHID (BATCH * HID)   // 32768
#define NB 8                 // batches per group
#define NU 16                // units per block
#define VROW 1064            // shorts/row: [h 512 | xhi 256 | xlo 256 | pad 40]
#define POISON 0x7f7f7f7fu

typedef __attribute__((ext_vector_type(8))) short bf16x8;
typedef __attribute__((ext_vector_type(4))) float f32x4;

__device__ __forceinline__ float4 llc_load4(const float* p) {
    float4 r; asm volatile("global_load_dwordx4 %0, %1, off sc0 sc1" : "=&v"(r) : "v"(p)); return r;
}
__device__ __forceinline__ void llc_store1(float* p, float v) {
    asm volatile("global_store_dword %0, %1, off sc0 sc1" :: "v"(p), "v"(v) : "memory");
}
__device__ __forceinline__ unsigned short f2bf(float f) {   // RNE float->bf16
    unsigned u = __float_as_uint(f);
    return (unsigned short)((u + 0x7fffu + ((u >> 16) & 1u)) >> 16);
}

__global__ __launch_bounds__(256, 1)
void lstm_persistent(const float* __restrict__ seqs,
                     const float* __restrict__ h0,
                     const float* __restrict__ c0,
                     const float* __restrict__ Wi, const float* __restrict__ bi,
                     const float* __restrict__ Wf, const float* __restrict__ bff,
                     const float* __restrict__ Wg, const float* __restrict__ bg,
                     const float* __restrict__ Wo, const float* __restrict__ bo,
                     float* __restrict__ out)   // [T+2][B][H]: h0, h1..hT, cT
{
    __shared__ __align__(16) short vv[NB * VROW];   // 17024 B — only LDS

    const int tid  = threadIdx.x;
    const int bid  = blockIdx.x;
    const int g    = bid >> 5;         // group 0..7: batches [8g, 8g+8)
    const int rblk = bid & 31;         // 0..31: units [16r, 16r+16)
    const int b0 = g * NB;
    const int u0 = rblk * NU;

    const int wv  = tid >> 6;          // wave: owns units u0+4wv .. +3
    const int l   = tid & 63;
    const int n16 = l & 15;            // A row idx / D col (batch)
    const int khi = (l >> 4) & 3;      // k-subgroup / D row group (unit)
    const int bbr = l & 7;             // B-frag batch row (8-15 broadcast-dup)

    // ---- weights: lane n16 loads row (gate = n16&3, u_local = n16>>2) ----
    const int gsel = n16 & 3;
    const float* Wsel = (gsel == 0) ? Wi : (gsel == 1) ? Wf : (gsel == 2) ? Wg : Wo;
    const float* wrow = Wsel + (size_t)(u0 + 4 * wv + (n16 >> 2)) * KTOT;
    bf16x8 whi[24], wlo[24];
#pragma unroll
    for (int kt = 0; kt < 24; ++kt) {
        const int k0 = kt * 32 + khi * 8;
        const float4 a = *reinterpret_cast<const float4*>(wrow + k0);
        const float4 b = *reinterpret_cast<const float4*>(wrow + k0 + 4);
        const float vals[8] = {a.x, a.y, a.z, a.w, b.x, b.y, b.z, b.w};
        bf16x8 h8, l8;
#pragma unroll
        for (int i = 0; i < 8; ++i) {
            const unsigned short hv = f2bf(vals[i]);
            h8[i] = (short)hv;
            l8[i] = (short)f2bf(vals[i] - __uint_as_float((unsigned)hv << 16));
        }
        whi[kt] = h8; wlo[kt] = l8;
    }

    // ---- per-lane epilogue state: biases + c (unit_d, batch_d) ----
    const int unit_d  = u0 + 4 * wv + khi;
    const int batch_d = b0 + (n16 & 7);          // lanes 8-15 unused in E
    const float bI = bi[unit_d],  bF = bff[unit_d];
    const float bG = bg[unit_d],  bO = bo[unit_d];
    float creg = c0[(size_t)batch_d * HID + unit_d];

    if (tid < 128) {   // allhidden[0] = h0 slice (plain; never polled)
        const int uu = tid & 15, bb = tid >> 4;
        out[(size_t)(b0 + bb) * HID + u0 + uu] = h0[(size_t)(b0 + bb) * HID + u0 + uu];
    }

    // ---- pre-loop staging: h0 (bf16-hi) and x0 (hi+lo) -> LDS ----
    {
        const int b = tid >> 5, k0 = (tid & 31) * 16;
        const float* hp = h0 + (size_t)(b0 + b) * HID + k0;
        float hv[16];
#pragma unroll
        for (int i = 0; i < 4; ++i) {
            const float4 t4 = reinterpret_cast<const float4*>(hp)[i];
            hv[4*i] = t4.x; hv[4*i+1] = t4.y; hv[4*i+2] = t4.z; hv[4*i+3] = t4.w;
        }
        bf16x8 a8, b8;
#pragma unroll
        for (int i = 0; i < 8; ++i) { a8[i] = (short)f2bf(hv[i]); b8[i] = (short)f2bf(hv[8+i]); }
        *reinterpret_cast<bf16x8*>(&vv[b * VROW + k0])     = a8;
        *reinterpret_cast<bf16x8*>(&vv[b * VROW + k0 + 8]) = b8;
    }
    if (tid < 128) {
        const int b = tid >> 4, kx = (tid & 15) * 16;
        const float* xp = seqs + (size_t)(b0 + b) * DIN + kx;
        float xv[16];
#pragma unroll
        for (int i = 0; i < 4; ++i) {
            const float4 t4 = reinterpret_cast<const float4*>(xp)[i];
            xv[4*i] = t4.x; xv[4*i+1] = t4.y; xv[4*i+2] = t4.z; xv[4*i+3] = t4.w;
        }
        bf16x8 a8, b8, la8, lb8;
#pragma unroll
        for (int i = 0; i < 8; ++i) {
            const unsigned short h1 = f2bf(xv[i]);
            a8[i] = (short)h1; la8[i] = (short)f2bf(xv[i] - __uint_as_float((unsigned)h1 << 16));
            const unsigned short h2 = f2bf(xv[8+i]);
            b8[i] = (short)h2; lb8[i] = (short)f2bf(xv[8+i] - __uint_as_float((unsigned)h2 << 16));
        }
        *reinterpret_cast<bf16x8*>(&vv[b * VROW + 512 + kx])     = a8;
        *reinterpret_cast<bf16x8*>(&vv[b * VROW + 512 + kx + 8]) = b8;
        *reinterpret_cast<bf16x8*>(&vv[b * VROW + 768 + kx])     = la8;
        *reinterpret_cast<bf16x8*>(&vv[b * VROW + 768 + kx + 8]) = lb8;
    }
    __syncthreads();

    const short* vrow = &vv[bbr * VROW + khi * 8];

    for (int t = 0; t < TSTEPS; ++t) {
        // ---- A: x-part MFMA (uses x_t; overlaps other blocks' h_t tails) ----
        f32x4 aA = {0.f,0.f,0.f,0.f}, aB = {0.f,0.f,0.f,0.f}, aC = {0.f,0.f,0.f,0.f};
#pragma unroll
        for (int kt = 0; kt < 8; ++kt) {
            const bf16x8 bh = *reinterpret_cast<const bf16x8*>(vrow + 512 + kt * 32);
            const bf16x8 bl = *reinterpret_cast<const bf16x8*>(vrow + 768 + kt * 32);
            aA = __builtin_amdgcn_mfma_f32_16x16x32_bf16(whi[16 + kt], bh, aA, 0, 0, 0);
            aB = __builtin_amdgcn_mfma_f32_16x16x32_bf16(wlo[16 + kt], bh, aB, 0, 0, 0);
            aC = __builtin_amdgcn_mfma_f32_16x16x32_bf16(whi[16 + kt], bl, aC, 0, 0, 0);
        }

        // ---- B: issue x_{t+1} loads (complete under C/D) ----
        float4 xr[4];
        const bool do_x = (t + 1 < TSTEPS) && (tid < 128);
        if (do_x) {
            const float* xp = seqs + (size_t)(t + 1) * BATCH * DIN
                            + (size_t)(b0 + (tid >> 4)) * DIN + (tid & 15) * 16;
#pragma unroll
            for (int i = 0; i < 4; ++i) xr[i] = reinterpret_cast<const float4*>(xp)[i];
        }

        // ---- C (t>0): speculative bulk poll — data is its own flag ----
        if (t > 0) {
            const int b = tid >> 5, k0 = (tid & 31) * 16;
            const float* hp = out + (size_t)t * BHID + (size_t)(b0 + b) * HID + k0;
            float4 hb[4];
            unsigned miss = 0;
            for (;;) {
#pragma unroll
                for (int i = 0; i < 4; ++i) hb[i] = llc_load4(hp + 4 * i);
                asm volatile("s_waitcnt vmcnt(0)" ::: "memory");
                __builtin_amdgcn_sched_barrier(0);
                bool ok = true;
#pragma unroll
                for (int i = 0; i < 4; ++i) {
                    ok &= (__float_as_uint(hb[i].x) != POISON);
                    ok &= (__float_as_uint(hb[i].y) != POISON);
                    ok &= (__float_as_uint(hb[i].z) != POISON);
                    ok &= (__float_as_uint(hb[i].w) != POISON);
                }
                if (ok) break;                    // per-thread readiness only
                if (++miss > (1u << 20)) break;   // bounded: never hang
                __builtin_amdgcn_s_sleep(1);      // ease LLC churn during skew
            }
            float hv[16];
#pragma unroll
            for (int i = 0; i < 4; ++i) {
                hv[4*i] = hb[i].x; hv[4*i+1] = hb[i].y; hv[4*i+2] = hb[i].z; hv[4*i+3] = hb[i].w;
            }
            bf16x8 a8, b8;
#pragma unroll
            for (int i = 0; i < 8; ++i) { a8[i] = (short)f2bf(hv[i]); b8[i] = (short)f2bf(hv[8+i]); }
            *reinterpret_cast<bf16x8*>(&vv[b * VROW + k0])     = a8;
            *reinterpret_cast<bf16x8*>(&vv[b * VROW + k0 + 8]) = b8;
        }
        __syncthreads();   // h_t staged block-wide

        // ---- D: h-part MFMA (2 chains, h bf16-hi) ----
#pragma unroll
        for (int kt = 0; kt < 16; ++kt) {
            const bf16x8 bh = *reinterpret_cast<const bf16x8*>(vrow + kt * 32);
            aA = __builtin_amdgcn_mfma_f32_16x16x32_bf16(whi[kt], bh, aA, 0, 0, 0);
            aB = __builtin_amdgcn_mfma_f32_16x16x32_bf16(wlo[kt], bh, aB, 0, 0, 0);
        }
        const f32x4 gA = aA + aB + aC;   // gA[r] = gate r of (unit_d, batch_d)

        // ---- E: lane-local elementwise + fire-and-forget dword h store ----
        if (n16 < 8) {
            const float gi = gA[0] + bI;
            const float gf = gA[1] + bF;
            const float gG = gA[2] + bG;
            const float go = gA[3] + bO;
            const float i_ = 1.f / (1.f + __expf(-gi));
            const float f_ = 1.f / (1.f + __expf(-gf));
            const float o_ = 1.f / (1.f + __expf(-go));
            float eg = __expf(-2.f * fabsf(gG));
            float tg = (1.f - eg) / (1.f + eg);
            tg = (gG < 0.f) ? -tg : tg;
            creg = f_ * creg + i_ * tg;
            float ec = __expf(-2.f * fabsf(creg));
            float tc = (1.f - ec) / (1.f + ec);
            tc = (creg < 0.f) ? -tc : tc;
            const float hn = o_ * tc;
            llc_store1(out + (size_t)(t + 1) * BHID + (size_t)batch_d * HID + unit_d, hn);
            if (t == TSTEPS - 1)
                out[(size_t)(TSTEPS + 1) * BHID + (size_t)batch_d * HID + unit_d] = creg;
        }

        // ---- F: x_{t+1} cvt -> LDS ----
        if (do_x) {
            const int b = tid >> 4, kx = (tid & 15) * 16;
            float xv[16];
#pragma unroll
            for (int i = 0; i < 4; ++i) {
                xv[4*i] = xr[i].x; xv[4*i+1] = xr[i].y; xv[4*i+2] = xr[i].z; xv[4*i+3] = xr[i].w;
            }
            bf16x8 a8, b8, la8, lb8;
#pragma unroll
            for (int i = 0; i < 8; ++i) {
                const unsigned short h1 = f2bf(xv[i]);
                a8[i] = (short)h1; la8[i] = (short)f2bf(xv[i] - __uint_as_float((unsigned)h1 << 16));
                const unsigned short h2 = f2bf(xv[8+i]);
                b8[i] = (short)h2; lb8[i] = (short)f2bf(xv[8+i] - __uint_as_float((unsigned)h2 << 16));
            }
            *reinterpret_cast<bf16x8*>(&vv[b * VROW + 512 + kx])     = a8;
            *reinterpret_cast<bf16x8*>(&vv[b * VROW + 512 + kx + 8]) = b8;
            *reinterpret_cast<bf16x8*>(&vv[b * VROW + 768 + kx])     = la8;
            *reinterpret_cast<bf16x8*>(&vv[b * VROW + 768 + kx + 8]) = lb8;
        }
        __syncthreads();   // x_{t+1} staged; h region free for next C
    }
}

extern "C" void kernel_launch(void* const* d_in, const int* in_sizes, int n_in,
                              void* d_out, int out_size, void* d_ws, size_t ws_size,
                              hipStream_t stream) {
    const float* seqs = (const float*)d_in[0];
    const float* h0   = (const float*)d_in[1];
    const float* c0   = (const float*)d_in[2];
    const float* Wi   = (const float*)d_in[3];
    const float* bi   = (const float*)d_in[4];
    const float* Wf   = (const float*)d_in[5];
    const float* bf   = (const float*)d_in[6];
    const float* Wg   = (const float*)d_in[7];
    const float* bg   = (const float*)d_in[8];
    const float* Wo   = (const float*)d_in[9];
    const float* bo   = (const float*)d_in[10];
    float* out = (float*)d_out;

    // Poison h[1..T] every launch: each element is written exactly once per
    // run, so the data itself is the readiness flag (graph-replay safe).
    hipMemsetAsync((char*)out + (size_t)BHID * 4, 0x7f,
                   (size_t)TSTEPS * BHID * 4, stream);

    hipLaunchKernelGGL(lstm_persistent, dim3(256), dim3(256), 0, stream,
                       seqs, h0, c0, Wi, bi, Wf, bf, Wg, bg, Wo, bo, out);
}

// Round 15
// 1250.971 us; speedup vs baseline: 28.9469x; 1.0833x over previous
//
#include <hip/hip_runtime.h>

// LSTM scan, persistent, per-element-poison sync + split-bf16 MFMA,
// all-gates-in-lane epilogue. T=512, B=64, D=256, H=512, K=768.
// R15: NU=32 / 512-thread blocks -> 8 groups x 16 blocks (128 total, 1/CU).
// Halves producers-per-group (skew tail) and poll-traffic (LLC congestion);
// we are latency-bound, so idling half the CUs is free.
// Proven sync (R10/R14): h elements self-flagging f32 dwords (poison
// 0x7f7f7f7f, each written once/run) through out; producers fire-and-forget
// sc0 sc1 dword stores; consumers speculatively bulk-load + per-thread retry.
// Lessons: LLC-only cross-CU visibility (R6/R7); only plain DWORD sc0 sc1
// stores proven visible (R11-13 NaNs: sub-dword/packed write-through never
// became visible -> poll timeout -> poison staged); explicit vmcnt +
// sched_barrier after asm loads (R8); "=&v" early-clobber; bounded polls.

#define TSTEPS 512
#define BATCH 64
#define DIN 256
#define HID 512
#define KTOT 768
#define BHID (BATCH * HID)   // 32768
#define NB 8                 // batches per group
#define NU 32                // units per block
#define VROW 1064            // shorts/row: [h 512 | xhi 256 | xlo 256 | pad 40]
#define POISON 0x7f7f7f7fu

typedef __attribute__((ext_vector_type(8))) short bf16x8;
typedef __attribute__((ext_vector_type(4))) float f32x4;

__device__ __forceinline__ float4 llc_load4(const float* p) {
    float4 r; asm volatile("global_load_dwordx4 %0, %1, off sc0 sc1" : "=&v"(r) : "v"(p)); return r;
}
__device__ __forceinline__ void llc_store1(float* p, float v) {
    asm volatile("global_store_dword %0, %1, off sc0 sc1" :: "v"(p), "v"(v) : "memory");
}
__device__ __forceinline__ unsigned short f2bf(float f) {   // RNE float->bf16
    unsigned u = __float_as_uint(f);
    return (unsigned short)((u + 0x7fffu + ((u >> 16) & 1u)) >> 16);
}

__global__ __launch_bounds__(512, 1)
void lstm_persistent(const float* __restrict__ seqs,
                     const float* __restrict__ h0,
                     const float* __restrict__ c0,
                     const float* __restrict__ Wi, const float* __restrict__ bi,
                     const float* __restrict__ Wf, const float* __restrict__ bff,
                     const float* __restrict__ Wg, const float* __restrict__ bg,
                     const float* __restrict__ Wo, const float* __restrict__ bo,
                     float* __restrict__ out)   // [T+2][B][H]: h0, h1..hT, cT
{
    __shared__ __align__(16) short vv[NB * VROW];   // 17024 B

    const int tid  = threadIdx.x;
    const int bid  = blockIdx.x;
    const int g    = bid >> 4;         // group 0..7: batches [8g, 8g+8)
    const int rblk = bid & 15;         // 0..15: units [32r, 32r+32)
    const int b0 = g * NB;
    const int u0 = rblk * NU;

    const int wv  = tid >> 6;          // wave 0..7: owns units u0+4wv .. +3
    const int l   = tid & 63;
    const int n16 = l & 15;            // A row idx / D col (batch)
    const int khi = (l >> 4) & 3;      // k-subgroup / D row group (unit)
    const int bbr = l & 7;             // B-frag batch row (8-15 broadcast-dup)

    // ---- weights: lane n16 loads row (gate = n16&3, u_local = n16>>2) ----
    const int gsel = n16 & 3;
    const float* Wsel = (gsel == 0) ? Wi : (gsel == 1) ? Wf : (gsel == 2) ? Wg : Wo;
    const float* wrow = Wsel + (size_t)(u0 + 4 * wv + (n16 >> 2)) * KTOT;
    bf16x8 whi[24], wlo[24];
#pragma unroll
    for (int kt = 0; kt < 24; ++kt) {
        const int k0 = kt * 32 + khi * 8;
        const float4 a = *reinterpret_cast<const float4*>(wrow + k0);
        const float4 b = *reinterpret_cast<const float4*>(wrow + k0 + 4);
        const float vals[8] = {a.x, a.y, a.z, a.w, b.x, b.y, b.z, b.w};
        bf16x8 h8, l8;
#pragma unroll
        for (int i = 0; i < 8; ++i) {
            const unsigned short hv = f2bf(vals[i]);
            h8[i] = (short)hv;
            l8[i] = (short)f2bf(vals[i] - __uint_as_float((unsigned)hv << 16));
        }
        whi[kt] = h8; wlo[kt] = l8;
    }

    // ---- per-lane epilogue state: biases + c (unit_d, batch_d) ----
    const int unit_d  = u0 + 4 * wv + khi;
    const int batch_d = b0 + (n16 & 7);          // lanes 8-15 unused in E
    const float bI = bi[unit_d],  bF = bff[unit_d];
    const float bG = bg[unit_d],  bO = bo[unit_d];
    float creg = c0[(size_t)batch_d * HID + unit_d];

    if (tid < 256) {   // allhidden[0] = h0 slice (plain; never polled)
        const int uu = tid & 31, bb = tid >> 5;
        out[(size_t)(b0 + bb) * HID + u0 + uu] = h0[(size_t)(b0 + bb) * HID + u0 + uu];
    }

    // ---- pre-loop staging: h0 (bf16-hi) and x0 (hi+lo) -> LDS ----
    {
        const int b = tid >> 6, k0 = (tid & 63) * 8;
        const float* hp = h0 + (size_t)(b0 + b) * HID + k0;
        const float4 t0 = reinterpret_cast<const float4*>(hp)[0];
        const float4 t1 = reinterpret_cast<const float4*>(hp)[1];
        const float hv[8] = {t0.x, t0.y, t0.z, t0.w, t1.x, t1.y, t1.z, t1.w};
        bf16x8 a8;
#pragma unroll
        for (int i = 0; i < 8; ++i) a8[i] = (short)f2bf(hv[i]);
        *reinterpret_cast<bf16x8*>(&vv[b * VROW + k0]) = a8;
    }
    if (tid < 256) {
        const int b = tid >> 5, kx = (tid & 31) * 8;
        const float* xp = seqs + (size_t)(b0 + b) * DIN + kx;
        const float4 t0 = reinterpret_cast<const float4*>(xp)[0];
        const float4 t1 = reinterpret_cast<const float4*>(xp)[1];
        const float xv[8] = {t0.x, t0.y, t0.z, t0.w, t1.x, t1.y, t1.z, t1.w};
        bf16x8 a8, la8;
#pragma unroll
        for (int i = 0; i < 8; ++i) {
            const unsigned short h1 = f2bf(xv[i]);
            a8[i]  = (short)h1;
            la8[i] = (short)f2bf(xv[i] - __uint_as_float((unsigned)h1 << 16));
        }
        *reinterpret_cast<bf16x8*>(&vv[b * VROW + 512 + kx]) = a8;
        *reinterpret_cast<bf16x8*>(&vv[b * VROW + 768 + kx]) = la8;
    }
    __syncthreads();

    const short* vrow = &vv[bbr * VROW + khi * 8];

    for (int t = 0; t < TSTEPS; ++t) {
        // ---- C0: issue speculative h_t loads BEFORE the x-MFMA phase ----
        const int cb = tid >> 6, ck = (tid & 63) * 8;
        const float* hpf = out + (size_t)t * BHID + (size_t)(b0 + cb) * HID + ck;
        float4 hb0, hb1;
        if (t > 0) { hb0 = llc_load4(hpf); hb1 = llc_load4(hpf + 4); }

        // ---- A: x-part MFMA (uses x_t; overlaps other blocks' h_t tails) ----
        f32x4 aA = {0.f,0.f,0.f,0.f}, aB = {0.f,0.f,0.f,0.f}, aC = {0.f,0.f,0.f,0.f};
#pragma unroll
        for (int kt = 0; kt < 8; ++kt) {
            const bf16x8 bh = *reinterpret_cast<const bf16x8*>(vrow + 512 + kt * 32);
            const bf16x8 bl = *reinterpret_cast<const bf16x8*>(vrow + 768 + kt * 32);
            aA = __builtin_amdgcn_mfma_f32_16x16x32_bf16(whi[16 + kt], bh, aA, 0, 0, 0);
            aB = __builtin_amdgcn_mfma_f32_16x16x32_bf16(wlo[16 + kt], bh, aB, 0, 0, 0);
            aC = __builtin_amdgcn_mfma_f32_16x16x32_bf16(whi[16 + kt], bl, aC, 0, 0, 0);
        }

        // ---- B: issue x_{t+1} loads (complete under C/D) ----
        float4 xr0, xr1;
        const bool do_x = (t + 1 < TSTEPS) && (tid < 256);
        if (do_x) {
            const float* xp = seqs + (size_t)(t + 1) * BATCH * DIN
                            + (size_t)(b0 + (tid >> 5)) * DIN + (tid & 31) * 8;
            xr0 = reinterpret_cast<const float4*>(xp)[0];
            xr1 = reinterpret_cast<const float4*>(xp)[1];
        }

        // ---- C (t>0): speculative poll — data is its own flag ----
        if (t > 0) {
            unsigned miss = 0;
            for (;;) {
                asm volatile("s_waitcnt vmcnt(0)" ::: "memory");
                __builtin_amdgcn_sched_barrier(0);
                bool ok = true;
                ok &= (__float_as_uint(hb0.x) != POISON);
                ok &= (__float_as_uint(hb0.y) != POISON);
                ok &= (__float_as_uint(hb0.z) != POISON);
                ok &= (__float_as_uint(hb0.w) != POISON);
                ok &= (__float_as_uint(hb1.x) != POISON);
                ok &= (__float_as_uint(hb1.y) != POISON);
                ok &= (__float_as_uint(hb1.z) != POISON);
                ok &= (__float_as_uint(hb1.w) != POISON);
                if (ok) break;                    // per-thread readiness only
                if (++miss > (1u << 20)) break;   // bounded: never hang
                __builtin_amdgcn_s_sleep(1);
                hb0 = llc_load4(hpf); hb1 = llc_load4(hpf + 4);
            }
            const float hv[8] = {hb0.x, hb0.y, hb0.z, hb0.w, hb1.x, hb1.y, hb1.z, hb1.w};
            bf16x8 a8;
#pragma unroll
            for (int i = 0; i < 8; ++i) a8[i] = (short)f2bf(hv[i]);
            *reinterpret_cast<bf16x8*>(&vv[cb * VROW + ck]) = a8;
        }
        __syncthreads();   // h_t staged block-wide

        // ---- D: h-part MFMA (2 chains, h bf16-hi) ----
#pragma unroll
        for (int kt = 0; kt < 16; ++kt) {
            const bf16x8 bh = *reinterpret_cast<const bf16x8*>(vrow + kt * 32);
            aA = __builtin_amdgcn_mfma_f32_16x16x32_bf16(whi[kt], bh, aA, 0, 0, 0);
            aB = __builtin_amdgcn_mfma_f32_16x16x32_bf16(wlo[kt], bh, aB, 0, 0, 0);
        }
        const f32x4 gA = aA + aB + aC;   // gA[r] = gate r of (unit_d, batch_d)

        // ---- E: lane-local elementwise + fire-and-forget dword h store ----
        if (n16 < 8) {
            const float gi = gA[0] + bI;
            const float gf = gA[1] + bF;
            const float gG = gA[2] + bG;
            const float go = gA[3] + bO;
            const float i_ = 1.f / (1.f + __expf(-gi));
            const float f_ = 1.f / (1.f + __expf(-gf));
            const float o_ = 1.f / (1.f + __expf(-go));
            float eg = __expf(-2.f * fabsf(gG));
            float tg = (1.f - eg) / (1.f + eg);
            tg = (gG < 0.f) ? -tg : tg;
            creg = f_ * creg + i_ * tg;
            float ec = __expf(-2.f * fabsf(creg));
            float tc = (1.f - ec) / (1.f + ec);
            tc = (creg < 0.f) ? -tc : tc;
            const float hn = o_ * tc;
            llc_store1(out + (size_t)(t + 1) * BHID + (size_t)batch_d * HID + unit_d, hn);
            if (t == TSTEPS - 1)
                out[(size_t)(TSTEPS + 1) * BHID + (size_t)batch_d * HID + unit_d] = creg;
        }

        // ---- F: x_{t+1} cvt -> LDS ----
        if (do_x) {
            const int b = tid >> 5, kx = (tid & 31) * 8;
            const float xv[8] = {xr0.x, xr0.y, xr0.z, xr0.w, xr1.x, xr1.y, xr1.z, xr1.w};
            bf16x8 a8, la8;
#pragma unroll
            for (int i = 0; i < 8; ++i) {
                const unsigned short h1 = f2bf(xv[i]);
                a8[i]  = (short)h1;
                la8[i] = (short)f2bf(xv[i] - __uint_as_float((unsigned)h1 << 16));
            }
            *reinterpret_cast<bf16x8*>(&vv[b * VROW + 512 + kx]) = a8;
            *reinterpret_cast<bf16x8*>(&vv[b * VROW + 768 + kx]) = la8;
        }
        __syncthreads();   // x_{t+1} staged; h region free for next C
    }
}

extern "C" void kernel_launch(void* const* d_in, const int* in_sizes, int n_in,
                              void* d_out, int out_size, void* d_ws, size_t ws_size,
                              hipStream_t stream) {
    const float* seqs = (const float*)d_in[0];
    const float* h0   = (const float*)d_in[1];
    const float* c0   = (const float*)d_in[2];
    const float* Wi   = (const float*)d_in[3];
    const float* bi   = (const float*)d_in[4];
    const float* Wf   = (const float*)d_in[5];
    const float* bf   = (const float*)d_in[6];
    const float* Wg   = (const float*)d_in[7];
    const float* bg   = (const float*)d_in[8];
    const float* Wo   = (const float*)d_in[9];
    const float* bo   = (const float*)d_in[10];
    float* out = (float*)d_out;

    // Poison h[1..T] every launch: each element is written exactly once per
    // run, so the data itself is the readiness flag (graph-replay safe).
    hipMemsetAsync((char*)out + (size_t)BHID * 4, 0x7f,
                   (size_t)TSTEPS * BHID * 4, stream);

    hipLaunchKernelGGL(lstm_persistent, dim3(128), dim3(512), 0, stream,
                       seqs, h0, c0, Wi, bi, Wf, bf, Wg, bg, Wo, bo, out);
}